// Round 1
// baseline (730.297 us; speedup 1.0000x reference)
//
#include <hip/hip_runtime.h>

// Problem constants: B=4096 rows, F=128 features, A=8 attention heads, U=10 units.
// y[b,f] = softmax_f( BN( (1/F) * sum_{j,a,u} softmax_u(Z[j,a,b,:])[u] * exp(2*K[j,a,f,u]) * fc_w[a] + fc_b ) )
// Z[j,a,b,u] = sum_f x[b,f]*K[j,a,f,u] - x[b,j]*K[j,a,j,u]

#define NJ 8            // j-chunks (grid dim), partial-y reduction in finalize
#define JPC (128 / NJ)  // j's per chunk

// ---------------------------------------------------------------------------
// Prep: Kp = K padded to [j,a,f,12] (16B-aligned rows for scalar dwordx4 loads)
//       Wp[j,a,u,f] = exp(2*K[j,a,f,u]) * fc_w[a] / 128   (transposed, f contig)
// ---------------------------------------------------------------------------
__global__ void ife_prep(const float* __restrict__ K, const float* __restrict__ fc_w,
                         float* __restrict__ Kp, float* __restrict__ Wp) {
    int t = blockIdx.x * 256 + threadIdx.x;       // (j*8+a)*128 + f
    if (t >= 128 * 8 * 128) return;
    int ja = t >> 7;
    int f  = t & 127;
    int a  = ja & 7;
    float wscale = fc_w[a] * (1.0f / 128.0f);
    const float* src = K + (size_t)t * 10;
    float* kd = Kp + (size_t)t * 12;
    float* wd = Wp + (size_t)ja * 10 * 128 + f;
#pragma unroll
    for (int u = 0; u < 10; ++u) {
        float v = src[u];
        kd[u] = v;
        wd[u * 128] = __expf(2.0f * v) * wscale;
    }
    kd[10] = 0.0f; kd[11] = 0.0f;
}

// ---------------------------------------------------------------------------
// Main fused kernel. Block = 256 threads (4 waves), owns a 64-row x-tile and
// one j-chunk. Per (j, a-quad): phase1 GEMM1+softmax (wave=a, lane=row),
// phase2 rank-10 update into register y-tile (wave=f-quarter, lane=row).
// ---------------------------------------------------------------------------
__global__ __launch_bounds__(256, 3) void ife_main(
    const float* __restrict__ x, const float* __restrict__ Kp,
    const float* __restrict__ Wp, float* __restrict__ yp) {
    __shared__ float xs[64 * 128];      // x tile, XOR-swizzled float4s
    __shared__ float ps[4 * 64 * 13];   // P[a_off][row][u], stride 13 = conflict-free
    const int t     = threadIdx.x;
    const int btile = blockIdx.x & 63;
    const int chunk = blockIdx.x >> 6;
    const int b0    = btile * 64;

    // stage x tile: store float4 k at column (k ^ (row&7)) -> conflict-free reads
    for (int i = t; i < 64 * 32; i += 256) {
        int b = i >> 5, k = i & 31;
        float4 v = *reinterpret_cast<const float4*>(x + (size_t)(b0 + b) * 128 + k * 4);
        *reinterpret_cast<float4*>(xs + b * 128 + ((k ^ (b & 7)) << 2)) = v;
    }

    float4 acc[8];
#pragma unroll
    for (int r = 0; r < 8; ++r) acc[r] = float4{0.f, 0.f, 0.f, 0.f};

    const int lb = t & 63;                                   // row within tile
    const int wv = __builtin_amdgcn_readfirstlane(t >> 6);   // wave id (uniform)
    const int bx = lb & 7;
    __syncthreads();

    for (int jj = 0; jj < JPC; ++jj) {
        const int j = chunk * JPC + jj;
#pragma unroll 1
        for (int a4 = 0; a4 < 2; ++a4) {
            // ---------------- phase 1: Z row + softmax -> ps ----------------
            {
                const int a = a4 * 4 + wv;
                const float* kb = Kp + (size_t)((j * 8 + a) * 128) * 12;  // scalar-load base
                float z[10];
#pragma unroll
                for (int u = 0; u < 10; ++u) z[u] = 0.f;
                const float* xrow = xs + lb * 128;
#pragma unroll 1
                for (int k = 0; k < 32; ++k) {
                    float4 xv = *reinterpret_cast<const float4*>(xrow + ((k ^ bx) << 2));
                    const float* kk = kb + k * 48;
#pragma unroll
                    for (int u = 0; u < 10; ++u) z[u] = fmaf(xv.x, kk[u],      z[u]);
#pragma unroll
                    for (int u = 0; u < 10; ++u) z[u] = fmaf(xv.y, kk[12 + u], z[u]);
#pragma unroll
                    for (int u = 0; u < 10; ++u) z[u] = fmaf(xv.z, kk[24 + u], z[u]);
#pragma unroll
                    for (int u = 0; u < 10; ++u) z[u] = fmaf(xv.w, kk[36 + u], z[u]);
                }
                // remove masked feature j: -= x[b,j] * K[j,a,j,u]
                {
                    const int kj = j >> 2, dj = j & 3;
                    float xbj = xrow[((kj ^ bx) << 2) + dj];
                    const float* kd = kb + j * 12;
#pragma unroll
                    for (int u = 0; u < 10; ++u) z[u] = fmaf(-xbj, kd[u], z[u]);
                }
                // softmax over u (in-thread, U=10)
                float m = z[0];
#pragma unroll
                for (int u = 1; u < 10; ++u) m = fmaxf(m, z[u]);
                float ssum = 0.f;
#pragma unroll
                for (int u = 0; u < 10; ++u) { z[u] = __expf(z[u] - m); ssum += z[u]; }
                float inv = 1.0f / ssum;
                float* pd = ps + (wv * 64 + lb) * 13;
#pragma unroll
                for (int u = 0; u < 10; ++u) pd[u] = z[u] * inv;
            }
            __syncthreads();
            // ---------------- phase 2: acc += P ⊗ Wp ----------------
            {
                // wave-uniform Wp rows (scalar loads); lane-varying P (LDS b32)
                const float* wbase = Wp + (size_t)((j * 8 + a4 * 4) * 10) * 128 + wv * 32;
#pragma unroll
                for (int ao = 0; ao < 4; ++ao) {
                    const float* pb = ps + (ao * 64 + lb) * 13;
#pragma unroll
                    for (int u = 0; u < 10; ++u) {
                        const float* wrow = wbase + (ao * 10 + u) * 128;
                        float p = pb[u];
#pragma unroll
                        for (int c = 0; c < 8; ++c) {
                            float4 w4 = *reinterpret_cast<const float4*>(wrow + c * 4);
                            acc[c].x = fmaf(p, w4.x, acc[c].x);
                            acc[c].y = fmaf(p, w4.y, acc[c].y);
                            acc[c].z = fmaf(p, w4.z, acc[c].z);
                            acc[c].w = fmaf(p, w4.w, acc[c].w);
                        }
                    }
                }
            }
            __syncthreads();
        }
    }
    // store this chunk's partial y-tile
    float* yd = yp + ((size_t)chunk * 4096 + b0 + lb) * 128 + wv * 32;
#pragma unroll
    for (int c = 0; c < 8; ++c)
        *reinterpret_cast<float4*>(yd + c * 4) = acc[c];
}

// ---------------------------------------------------------------------------
// Finalize: sum NJ partials, + fc_b, inference BatchNorm, row-softmax over F.
// One block (128 threads = 2 waves) per row.
// ---------------------------------------------------------------------------
__global__ void ife_final(const float* __restrict__ yp, const float* __restrict__ fc_b,
                          const float* __restrict__ gamma, const float* __restrict__ beta,
                          const float* __restrict__ mmean, const float* __restrict__ mvar,
                          float* __restrict__ out) {
    const int b = blockIdx.x;
    const int f = threadIdx.x;  // 128
    float s = 0.f;
#pragma unroll
    for (int n = 0; n < NJ; ++n)
        s += yp[((size_t)n * 4096 + b) * 128 + f];
    const float scale = gamma[0] * rsqrtf(mvar[0] + 1e-3f);
    float y = (s + fc_b[0] - mmean[0]) * scale + beta[0];

    __shared__ float redm[2], reds[2];
    float m = y;
#pragma unroll
    for (int o = 32; o >= 1; o >>= 1) m = fmaxf(m, __shfl_xor(m, o, 64));
    const int wid = f >> 6;
    if ((f & 63) == 0) redm[wid] = m;
    __syncthreads();
    m = fmaxf(redm[0], redm[1]);
    float e = __expf(y - m);
    float ss = e;
#pragma unroll
    for (int o = 32; o >= 1; o >>= 1) ss += __shfl_xor(ss, o, 64);
    if ((f & 63) == 0) reds[wid] = ss;
    __syncthreads();
    out[(size_t)b * 128 + f] = e / (reds[0] + reds[1]);
}

// ---------------------------------------------------------------------------
extern "C" void kernel_launch(void* const* d_in, const int* in_sizes, int n_in,
                              void* d_out, int out_size, void* d_ws, size_t ws_size,
                              hipStream_t stream) {
    const float* x     = (const float*)d_in[0];
    const float* K     = (const float*)d_in[1];
    const float* fc_w  = (const float*)d_in[2];
    const float* fc_b  = (const float*)d_in[3];
    const float* gamma = (const float*)d_in[4];
    const float* beta  = (const float*)d_in[5];
    const float* mmean = (const float*)d_in[6];
    const float* mvar  = (const float*)d_in[7];
    float* out = (float*)d_out;

    float* ws = (float*)d_ws;
    float* Kp = ws;                    // 128*8*128*12 = 1,572,864 f (6.3 MB)
    float* Wp = ws + 1572864;          // 128*8*10*128 = 1,310,720 f (5.2 MB)
    float* yp = ws + 2883584;          // NJ*4096*128  = 4,194,304 f (16.8 MB)

    hipLaunchKernelGGL(ife_prep,  dim3(512),     dim3(256), 0, stream, K, fc_w, Kp, Wp);
    hipLaunchKernelGGL(ife_main,  dim3(64 * NJ), dim3(256), 0, stream, x, Kp, Wp, yp);
    hipLaunchKernelGGL(ife_final, dim3(4096),    dim3(128), 0, stream,
                       yp, fc_b, gamma, beta, mmean, mvar, out);
}

// Round 3
// 179.179 us; speedup vs baseline: 4.0758x; 4.0758x over previous
//
#include <hip/hip_runtime.h>

// B=4096 rows, F=128 features, A=8 heads, U=10 units (padded to 16).
// y = softmax_f( BN( (1/F) sum_{j,a,u} softmax_u(Z[j,a,b,:])[u] exp(2K[j,a,f,u]) fc_w[a] + fc_b ) )
// Z[j,a,b,u] = sum_f x[b,f] K[j,a,f,u] - x[b,j] K[j,a,j,u]
//
// MFMA plan (16x16x32 bf16, fp32 accum):
//   GEMM1 (transposed): Z^T[u][b] = KbT[u][f] * x[f][b]  -> u lives in-lane for softmax
//   GEMM2: acc[b][f] += P[b][k=(a-pair,u)] * W2[k][f], k=32 packs 2 heads per MFMA

#define NJ 8            // j-chunks; partials reduced in finalize
#define JPC (128 / NJ)

typedef __attribute__((ext_vector_type(8))) short short8v;
typedef __attribute__((ext_vector_type(4))) float f32x4;

__device__ inline unsigned short f2bf(float f) {
    union { float f; unsigned u; } c; c.f = f;
    return (unsigned short)((c.u + 0x7FFFu + ((c.u >> 16) & 1u)) >> 16);
}
__device__ inline float bf2f(unsigned short h) {
    union { unsigned u; float f; } c; c.u = ((unsigned)h) << 16;
    return c.f;
}

// ---------------------------------------------------------------------------
// Prep: KbT[j][a][u16][f128] bf16 (B^T for GEMM1, zero-padded u>=10)
//       W2 [j][p4][f128][k32] bf16, k = ai*16+u: exp(2K)*fc_w[a]/128 (0 for u>=10)
//       Kjj[j][a][u16] bf16 = K[j,a,j,u] (for the mask-j rank-1 correction)
// ---------------------------------------------------------------------------
__global__ void ife_prep2(const float* __restrict__ K, const float* __restrict__ fc_w,
                          unsigned short* __restrict__ KbT, unsigned short* __restrict__ W2,
                          unsigned short* __restrict__ Kjj) {
    int t = blockIdx.x * 256 + threadIdx.x;   // (j*8+a)*128 + f
    if (t >= 128 * 8 * 128) return;
    int ja = t >> 7, f = t & 127;
    int j = ja >> 3, a = ja & 7, p = a >> 1, ai = a & 1;
    float wscale = fc_w[a] * (1.0f / 128.0f);
    const float* src = K + (size_t)t * 10;
    unsigned short* w2 = W2 + (((size_t)(j * 4 + p) * 128 + f) * 32) + ai * 16;
#pragma unroll
    for (int u = 0; u < 16; ++u) {
        float kv = (u < 10) ? src[u] : 0.0f;
        unsigned short kb = (u < 10) ? f2bf(kv) : (unsigned short)0;
        KbT[((size_t)ja * 16 + u) * 128 + f] = kb;
        w2[u] = (u < 10) ? f2bf(__expf(2.0f * kv) * wscale) : (unsigned short)0;
        if (f == j) Kjj[ja * 16 + u] = kb;
    }
}

// ---------------------------------------------------------------------------
// Main: block = 256 threads (4 waves), 64-row b-tile, one j-chunk.
// Wave w: GEMM1+softmax for heads a=2w,2w+1 (pair w); GEMM2 f-block w*32.
// ---------------------------------------------------------------------------
__global__ __launch_bounds__(256, 2) void ife_main2(
    const float* __restrict__ x, const unsigned short* __restrict__ KbT,
    const unsigned short* __restrict__ W2, const unsigned short* __restrict__ Kjj,
    float* __restrict__ yp) {
    __shared__ unsigned xb[64 * 64];    // x tile bf16x2, f-octet XOR-swizzled (16KB)
    __shared__ unsigned pb[4 * 64 * 16];// P bf16x2 [pair][b][k-dword], swizzled (16KB)

    const int t = threadIdx.x;
    const int btile = blockIdx.x & 63;
    const int chunk = blockIdx.x >> 6;
    const int b0 = btile * 64;
    const int lane = t & 63;
    const int wv = __builtin_amdgcn_readfirstlane(t >> 6);
    const int lr = lane & 15;   // row/col within a 16-tile
    const int lg = lane >> 4;   // k-octet group (0..3)

    // stage x -> bf16 LDS: dword dw holds f=2dw,2dw+1; octet g stored at g^(b&7)
    for (int i = t; i < 64 * 64; i += 256) {
        int b = i >> 6, dw = i & 63;
        float2 v = *reinterpret_cast<const float2*>(x + (size_t)(b0 + b) * 128 + dw * 2);
        unsigned pk = (unsigned)f2bf(v.x) | ((unsigned)f2bf(v.y) << 16);
        int g = dw >> 2;
        xb[b * 64 + (((g ^ (b & 7)) << 2) | (dw & 3))] = pk;
    }
    __syncthreads();

    // x B-fragments, j- and a-invariant: held in registers for the whole block.
    // frag(ks,nt): col b = nt*16+lr, k(f) = ks*32 + lg*8 .. +8
    short8v xf[16];
#pragma unroll
    for (int ks = 0; ks < 4; ++ks)
#pragma unroll
        for (int nt = 0; nt < 4; ++nt) {
            int b = nt * 16 + lr;
            int g = ks * 4 + lg;
            xf[ks * 4 + nt] = *reinterpret_cast<const short8v*>(
                &xb[b * 64 + ((g ^ (b & 7)) << 2)]);
        }

    f32x4 acc[4][2];
#pragma unroll
    for (int mt = 0; mt < 4; ++mt)
#pragma unroll
        for (int nt = 0; nt < 2; ++nt) acc[mt][nt] = f32x4{0.f, 0.f, 0.f, 0.f};

    const int ub = lg * 4;      // this lane's base u (GEMM1 D rows)

#pragma unroll 1
    for (int jj = 0; jj < JPC; ++jj) {
        const int j = chunk * JPC + jj;
        // ---------- GEMM1 + softmax + P-write for this wave's 2 heads ----------
#pragma unroll
        for (int ai = 0; ai < 2; ++ai) {
            const int a = wv * 2 + ai;
            const size_t kbase = (size_t)(j * 8 + a) * 16;
            short8v af[4];   // A-frag: row u=lr, k(f)=ks*32+lg*8
#pragma unroll
            for (int ks = 0; ks < 4; ++ks)
                af[ks] = *reinterpret_cast<const short8v*>(
                    KbT + (kbase + lr) * 128 + ks * 32 + lg * 8);
            f32x4 z[4];
#pragma unroll
            for (int nt = 0; nt < 4; ++nt) z[nt] = f32x4{0.f, 0.f, 0.f, 0.f};
#pragma unroll
            for (int ks = 0; ks < 4; ++ks)
#pragma unroll
                for (int nt = 0; nt < 4; ++nt)
                    z[nt] = __builtin_amdgcn_mfma_f32_16x16x32_bf16(
                        af[ks], xf[ks * 4 + nt], z[nt], 0, 0, 0);
            // rank-1 correction: z[u][b] -= K[j,a,j,u] * x[b,j]  (bf16 products)
            unsigned short kj0, kj1, kj2, kj3;
            {
                const unsigned short* kp = Kjj + kbase + ub;
                kj0 = kp[0]; kj1 = kp[1]; kj2 = kp[2]; kj3 = kp[3];
            }
            const int gj = j >> 3;
#pragma unroll
            for (int nt = 0; nt < 4; ++nt) {
                int b = nt * 16 + lr;
                unsigned pkx = xb[b * 64 + (((gj ^ (b & 7)) << 2) | ((j >> 1) & 3))];
                float xbj = bf2f((unsigned short)((j & 1) ? (pkx >> 16) : (pkx & 0xFFFFu)));
                z[nt][0] = fmaf(-bf2f(kj0), xbj, z[nt][0]);
                z[nt][1] = fmaf(-bf2f(kj1), xbj, z[nt][1]);
                z[nt][2] = fmaf(-bf2f(kj2), xbj, z[nt][2]);
                z[nt][3] = fmaf(-bf2f(kj3), xbj, z[nt][3]);
            }
            // softmax over u (in-lane 4 + shfl_xor 16/32), mask u>=10, pack to pb
#pragma unroll
            for (int nt = 0; nt < 4; ++nt) {
                float m = -3.0e38f;
#pragma unroll
                for (int q = 0; q < 4; ++q)
                    m = (ub + q < 10) ? fmaxf(m, z[nt][q]) : m;
                m = fmaxf(m, __shfl_xor(m, 16, 64));
                m = fmaxf(m, __shfl_xor(m, 32, 64));
                float e0 = (ub + 0 < 10) ? __expf(z[nt][0] - m) : 0.f;
                float e1 = (ub + 1 < 10) ? __expf(z[nt][1] - m) : 0.f;
                float e2 = (ub + 2 < 10) ? __expf(z[nt][2] - m) : 0.f;
                float e3 = (ub + 3 < 10) ? __expf(z[nt][3] - m) : 0.f;
                float s = e0 + e1 + e2 + e3;
                s += __shfl_xor(s, 16, 64);
                s += __shfl_xor(s, 32, 64);
                float inv = 1.0f / s;
                int b = nt * 16 + lr;
                unsigned pk0 = (unsigned)f2bf(e0 * inv) | ((unsigned)f2bf(e1 * inv) << 16);
                unsigned pk1 = (unsigned)f2bf(e2 * inv) | ((unsigned)f2bf(e3 * inv) << 16);
                int dw0 = ai * 8 + lg * 2;           // k-dword col (k = ai*16 + u)
                int base = (wv * 64 + b) * 16;
                int swz = (b >> 1) & 3;
                pb[base + ((((dw0 >> 2) ^ swz) << 2) | (dw0 & 3))] = pk0;
                pb[base + ((((dw0 + 1) >> 2) ^ swz) << 2) + ((dw0 + 1) & 3)] = pk1;
            }
        }
        __syncthreads();
        // ---------- GEMM2: acc[b][f-block wv*32] += P * W2 ----------
#pragma unroll
        for (int p = 0; p < 4; ++p) {
            short8v wf[2];   // B-frag: col f = wv*32+nt*16+lr, k = lg*8..+8
#pragma unroll
            for (int nt = 0; nt < 2; ++nt) {
                int f = wv * 32 + nt * 16 + lr;
                wf[nt] = *reinterpret_cast<const short8v*>(
                    W2 + (((size_t)(j * 4 + p) * 128 + f) * 32) + lg * 8);
            }
#pragma unroll
            for (int mt = 0; mt < 4; ++mt) {
                int b = mt * 16 + lr;
                short8v pf = *reinterpret_cast<const short8v*>(
                    &pb[(p * 64 + b) * 16 + ((lg ^ ((b >> 1) & 3)) << 2)]);
#pragma unroll
                for (int nt = 0; nt < 2; ++nt)
                    acc[mt][nt] = __builtin_amdgcn_mfma_f32_16x16x32_bf16(
                        pf, wf[nt], acc[mt][nt], 0, 0, 0);
            }
        }
        __syncthreads();
    }
    // store partials: D layout col=lr (f), row=lg*4+q (b)
    float* ypb = yp + ((size_t)chunk * 4096 + b0) * 128;
#pragma unroll
    for (int mt = 0; mt < 4; ++mt)
#pragma unroll
        for (int nt = 0; nt < 2; ++nt) {
            int f = wv * 32 + nt * 16 + lr;
#pragma unroll
            for (int q = 0; q < 4; ++q) {
                int b = mt * 16 + lg * 4 + q;
                ypb[(size_t)b * 128 + f] = acc[mt][nt][q];
            }
        }
}

// ---------------------------------------------------------------------------
// Finalize: sum NJ partials, + fc_b, inference BN, row-softmax over F=128.
// ---------------------------------------------------------------------------
__global__ void ife_final(const float* __restrict__ yp, const float* __restrict__ fc_b,
                          const float* __restrict__ gamma, const float* __restrict__ beta,
                          const float* __restrict__ mmean, const float* __restrict__ mvar,
                          float* __restrict__ out) {
    const int b = blockIdx.x;
    const int f = threadIdx.x;  // 128
    float s = 0.f;
#pragma unroll
    for (int n = 0; n < NJ; ++n)
        s += yp[((size_t)n * 4096 + b) * 128 + f];
    const float scale = gamma[0] * rsqrtf(mvar[0] + 1e-3f);
    float y = (s + fc_b[0] - mmean[0]) * scale + beta[0];

    __shared__ float redm[2], reds[2];
    float m = y;
#pragma unroll
    for (int o = 32; o >= 1; o >>= 1) m = fmaxf(m, __shfl_xor(m, o, 64));
    const int wid = f >> 6;
    if ((f & 63) == 0) redm[wid] = m;
    __syncthreads();
    m = fmaxf(redm[0], redm[1]);
    float e = __expf(y - m);
    float ss = e;
#pragma unroll
    for (int o = 32; o >= 1; o >>= 1) ss += __shfl_xor(ss, o, 64);
    if ((f & 63) == 0) reds[wid] = ss;
    __syncthreads();
    out[(size_t)b * 128 + f] = e / (reds[0] + reds[1]);
}

// ---------------------------------------------------------------------------
extern "C" void kernel_launch(void* const* d_in, const int* in_sizes, int n_in,
                              void* d_out, int out_size, void* d_ws, size_t ws_size,
                              hipStream_t stream) {
    const float* x     = (const float*)d_in[0];
    const float* K     = (const float*)d_in[1];
    const float* fc_w  = (const float*)d_in[2];
    const float* fc_b  = (const float*)d_in[3];
    const float* gamma = (const float*)d_in[4];
    const float* beta  = (const float*)d_in[5];
    const float* mmean = (const float*)d_in[6];
    const float* mvar  = (const float*)d_in[7];
    float* out = (float*)d_out;

    unsigned short* KbT = (unsigned short*)d_ws;            // 2,097,152 sh (4MB)
    unsigned short* W2  = KbT + 2097152;                    // 2,097,152 sh (4MB)
    unsigned short* Kjj = W2 + 2097152;                     // 16,384 sh
    float* yp = (float*)((char*)d_ws + 8421376);            // NJ*4096*128 f32 (16.8MB)

    hipLaunchKernelGGL(ife_prep2, dim3(512),     dim3(256), 0, stream, K, fc_w, KbT, W2, Kjj);
    hipLaunchKernelGGL(ife_main2, dim3(64 * NJ), dim3(256), 0, stream, x, KbT, W2, Kjj, yp);
    hipLaunchKernelGGL(ife_final, dim3(4096),    dim3(128), 0, stream,
                       yp, fc_b, gamma, beta, mmean, mvar, out);
}